// Round 1
// baseline (506.460 us; speedup 1.0000x reference)
//
#include <hip/hip_runtime.h>

// Problem constants (B=2, C=64, H=W=192, EXP=4, DG=4, K=3)
#define BN   2
#define CN   64
#define HN   192
#define WN   192
#define HWN  36864          // 192*192
#define OCN  256            // EXP*C
#define JCN  72             // DG*2*9
#define SN   32             // pixel strip length

// ---------------------------------------------------------------------------
// Prep: w2T[o][96] = padded transpose of w2 (72x256).
// Slot layout: 8 slots of 12 floats; slot js holds w2[js*9 + i][o] for i<9,
// zeros for i in 9..11 (pad keeps float4 alignment; zero weights are harmless).
// ---------------------------------------------------------------------------
__global__ __launch_bounds__(256) void k_prep(const float* __restrict__ w2,
                                              float* __restrict__ w2T) {
    int idx = blockIdx.x * 256 + threadIdx.x;       // 0 .. 256*96-1
    if (idx >= OCN * 96) return;
    int o  = idx / 96;
    int r  = idx - o * 96;
    int js = r / 12;
    int i  = r - js * 12;
    float v = 0.f;
    if (i < 9) v = w2[(js * 9 + i) * OCN + o];      // j = js*9+i  (<=71)
    w2T[idx] = v;
}

// ---------------------------------------------------------------------------
// Copy x1 -> output 0 (identity output), float4 vectorized.
// ---------------------------------------------------------------------------
__global__ __launch_bounds__(256) void k_copy(const float4* __restrict__ src,
                                              float4* __restrict__ dst, int n4) {
    int i = blockIdx.x * 256 + threadIdx.x;
    if (i < n4) dst[i] = src[i];
}

// ---------------------------------------------------------------------------
// K1: offsets t[b][j][y][x].
// Per block: one 32-pixel row strip. Phase1 stage x (64ch x 3rows x 34cols)
// in LDS; Phase2 compute xd (256 x 32) in LDS; Phase3 72x256 matvec.
// ---------------------------------------------------------------------------
__global__ __launch_bounds__(256) void k_offsets(const float* __restrict__ x,
                                                 const float* __restrict__ w1,
                                                 const float* __restrict__ w2T,
                                                 const float* __restrict__ b2,
                                                 float* __restrict__ t_out) {
    __shared__ float lds_x[CN * 3 * 34];   // 26.1 KB
    __shared__ float lds_xd[OCN * SN];     // 32.8 KB
    const int x0  = blockIdx.x * SN;
    const int y   = blockIdx.y;
    const int b   = blockIdx.z;
    const int tid = threadIdx.x;
    const float* xb = x + (size_t)b * CN * HWN;

    // Phase 1: stage x strip + halo (zero padded)
    for (int idx = tid; idx < CN * 3 * 34; idx += 256) {
        int c   = idx / 102;
        int rem = idx - c * 102;
        int r   = rem / 34;
        int col = rem - r * 34;
        int yy  = y - 1 + r;
        int xx  = x0 - 1 + col;
        float v = 0.f;
        if ((unsigned)yy < (unsigned)HN && (unsigned)xx < (unsigned)WN)
            v = xb[c * HWN + yy * WN + xx];
        lds_x[idx] = v;
    }
    __syncthreads();

    // Phase 2: xd[o][px] = sum_k w1[o][k] * (x_nbr - x_center)
    {
        const int px = tid & 31;
        const int cs = tid >> 5;                   // 0..7
        for (int i = 0; i < 8; ++i) {
            int c = cs * 8 + i;
            const float* lx = lds_x + c * 102;
            float ctr = lx[34 + px + 1];
            float d[9];
            #pragma unroll
            for (int k = 0; k < 9; ++k) {
                int r  = k / 3;
                int kx = k - r * 3;
                d[k] = lx[r * 34 + px + kx] - ctr;
            }
            #pragma unroll
            for (int e = 0; e < 4; ++e) {
                int o = c * 4 + e;
                const float* wr = w1 + o * 9;
                float acc = 0.f;
                #pragma unroll
                for (int k = 0; k < 9; ++k) acc += wr[k] * d[k];
                lds_xd[o * SN + px] = acc;
            }
        }
    }
    __syncthreads();

    // Phase 3: t[j] = b2[j] + sum_o w2[j][o] * xd[o],  9 j's per thread
    {
        const int px = tid & 31;
        const int js = tid >> 5;                   // 0..7 ; j = js*9 + i
        float acc[12];
        #pragma unroll
        for (int i = 0; i < 12; ++i) acc[i] = 0.f;
        #pragma unroll
        for (int i = 0; i < 9; ++i) acc[i] = b2[js * 9 + i];
        const float4* wrow = (const float4*)w2T + js * 3;  // float4 idx: o*24 + js*3
        #pragma unroll 4
        for (int o = 0; o < OCN; ++o) {
            float xv = lds_xd[o * SN + px];
            float4 wa = wrow[o * 24 + 0];
            float4 wb = wrow[o * 24 + 1];
            float4 wc = wrow[o * 24 + 2];
            acc[0]  += wa.x * xv; acc[1]  += wa.y * xv; acc[2]  += wa.z * xv; acc[3]  += wa.w * xv;
            acc[4]  += wb.x * xv; acc[5]  += wb.y * xv; acc[6]  += wb.z * xv; acc[7]  += wb.w * xv;
            acc[8]  += wc.x * xv; acc[9]  += wc.y * xv; acc[10] += wc.z * xv; acc[11] += wc.w * xv;
        }
        float* tb = t_out + (size_t)b * JCN * HWN + y * WN + x0 + px;
        #pragma unroll
        for (int i = 0; i < 9; ++i) {
            int j = js * 9 + i;
            tb[(size_t)j * HWN] = acc[i];
        }
    }
}

// ---------------------------------------------------------------------------
// K2: depthwise deformable conv + center correction -> y[b][c][h][w]
// ---------------------------------------------------------------------------
__device__ __forceinline__ float dsample(const float* __restrict__ p, int yi, int xi) {
    if ((unsigned)yi < (unsigned)HN && (unsigned)xi < (unsigned)WN)
        return p[yi * WN + xi];
    return 0.f;
}

__global__ __launch_bounds__(256) void k_deform(const float* __restrict__ x,
                                                const float* __restrict__ t_in,
                                                const float* __restrict__ wdef,
                                                float* __restrict__ y_out) {
    __shared__ float toff[JCN * SN];   // [j][px] 9.2 KB
    __shared__ float wk[CN * 9];
    __shared__ float wsum[CN];
    const int x0  = blockIdx.x * SN;
    const int yr  = blockIdx.y;
    const int b   = blockIdx.z;
    const int tid = threadIdx.x;

    const float* tb = t_in + (size_t)b * JCN * HWN + yr * WN + x0;
    for (int idx = tid; idx < JCN * SN; idx += 256) {
        int j  = idx >> 5;
        int px = idx & 31;
        toff[idx] = tb[(size_t)j * HWN + px];
    }
    for (int idx = tid; idx < CN * 9; idx += 256) wk[idx] = wdef[idx];
    if (tid < CN) {
        float s = 0.f;
        #pragma unroll
        for (int k = 0; k < 9; ++k) s += wdef[tid * 9 + k];
        wsum[tid] = s;
    }
    __syncthreads();

    const int px = tid & 31;
    const int cs = tid >> 5;
    for (int i = 0; i < 8; ++i) {
        int c = cs * 8 + i;
        int g = c >> 4;                           // deform group
        const float* xp = x + ((size_t)b * CN + c) * HWN;
        float xc  = xp[yr * WN + x0 + px];
        float acc = -xc * wsum[c];
        #pragma unroll
        for (int k = 0; k < 9; ++k) {
            int ky = k / 3;
            int kx = k - ky * 3;
            float dy = toff[((g * 9 + k) * 2 + 0) * SN + px];
            float dx = toff[((g * 9 + k) * 2 + 1) * SN + px];
            float py  = (float)(yr - 1 + ky) + dy;
            float pxf = (float)(x0 + px - 1 + kx) + dx;
            float y0f = floorf(py);
            float x0f = floorf(pxf);
            float wy = py - y0f;
            float wx = pxf - x0f;
            int yi = (int)y0f;
            int xi = (int)x0f;
            float v00 = dsample(xp, yi,     xi);
            float v01 = dsample(xp, yi,     xi + 1);
            float v10 = dsample(xp, yi + 1, xi);
            float v11 = dsample(xp, yi + 1, xi + 1);
            float bil = v00 * (1.f - wy) * (1.f - wx)
                      + v01 * (1.f - wy) * wx
                      + v10 * wy * (1.f - wx)
                      + v11 * wy * wx;
            acc += wk[c * 9 + k] * bil;
        }
        y_out[((size_t)b * CN + c) * HWN + yr * WN + x0 + px] = acc;
    }
}

// ---------------------------------------------------------------------------
// K3: m[b][o][h][w] = sum_c wout[o][c] * y[b][c][h][w]
// ---------------------------------------------------------------------------
__global__ __launch_bounds__(256) void k_final(const float* __restrict__ y_in,
                                               const float* __restrict__ wout,
                                               float* __restrict__ m_out) {
    __shared__ float lds_y[CN * SN];     // 8.2 KB
    __shared__ float ldsw[CN * CN];      // [c][o] 16.4 KB
    const int x0  = blockIdx.x * SN;
    const int yr  = blockIdx.y;
    const int b   = blockIdx.z;
    const int tid = threadIdx.x;

    for (int idx = tid; idx < CN * CN; idx += 256) {
        int c = idx >> 6;
        int o = idx & 63;
        ldsw[idx] = wout[o * CN + c];
    }
    for (int idx = tid; idx < CN * SN; idx += 256) {
        int c  = idx >> 5;
        int px = idx & 31;
        lds_y[idx] = y_in[((size_t)b * CN + c) * HWN + yr * WN + x0 + px];
    }
    __syncthreads();

    const int px = tid & 31;
    const int os = tid >> 5;                      // 0..7 -> 8 o's each
    float acc[8];
    #pragma unroll
    for (int i = 0; i < 8; ++i) acc[i] = 0.f;
    #pragma unroll 4
    for (int c = 0; c < CN; ++c) {
        float yv = lds_y[c * SN + px];
        const float4* wr = (const float4*)(ldsw + c * CN + os * 8);
        float4 wa = wr[0];
        float4 wb = wr[1];
        acc[0] += wa.x * yv; acc[1] += wa.y * yv; acc[2] += wa.z * yv; acc[3] += wa.w * yv;
        acc[4] += wb.x * yv; acc[5] += wb.y * yv; acc[6] += wb.z * yv; acc[7] += wb.w * yv;
    }
    #pragma unroll
    for (int i = 0; i < 8; ++i) {
        int o = os * 8 + i;
        m_out[((size_t)b * CN + o) * HWN + yr * WN + x0 + px] = acc[i];
    }
}

// ---------------------------------------------------------------------------
extern "C" void kernel_launch(void* const* d_in, const int* in_sizes, int n_in,
                              void* d_out, int out_size, void* d_ws, size_t ws_size,
                              hipStream_t stream) {
    const float* x1    = (const float*)d_in[0];   // 2*64*192*192
    const float* w_off1 = (const float*)d_in[1];  // 256*9
    const float* w_off2 = (const float*)d_in[2];  // 72*256
    const float* b_off2 = (const float*)d_in[3];  // 72
    const float* w_def = (const float*)d_in[4];   // 64*9
    const float* w_out = (const float*)d_in[5];   // 64*64

    float* out = (float*)d_out;
    const size_t n_x = (size_t)BN * CN * HWN;     // 4718592
    float* out_x1 = out;                          // output 0: x1 copy
    float* out_m  = out + n_x;                    // output 1: m

    // Workspace layout (floats)
    float* ws   = (float*)d_ws;
    float* w2T  = ws;                             // 256*96 = 24576
    float* t_ws = ws + 24576;                     // 2*72*36864 = 5308416
    float* y_ws = t_ws + (size_t)BN * JCN * HWN;  // 2*64*36864 = 4718592

    dim3 grid(WN / SN, HN, BN);                   // (6, 192, 2)
    dim3 blk(256);

    k_prep<<<dim3((OCN * 96 + 255) / 256), blk, 0, stream>>>(w_off2, w2T);
    k_copy<<<dim3((int)(n_x / 4 + 255) / 256), blk, 0, stream>>>(
        (const float4*)x1, (float4*)out_x1, (int)(n_x / 4));
    k_offsets<<<grid, blk, 0, stream>>>(x1, w_off1, w2T, b_off2, t_ws);
    k_deform<<<grid, blk, 0, stream>>>(x1, t_ws, w_def, y_ws);
    k_final<<<grid, blk, 0, stream>>>(y_ws, w_out, out_m);
}

// Round 2
// 441.625 us; speedup vs baseline: 1.1468x; 1.1468x over previous
//
#include <hip/hip_runtime.h>

// Problem constants (B=2, C=64, H=W=192, EXP=4, DG=4, K=3)
#define BN   2
#define CN   64
#define HN   192
#define WN   192
#define HWN  36864          // 192*192
#define OCN  256            // EXP*C
#define JCN  72             // DG*2*9
#define SN   32             // pixel strip length

// ---------------------------------------------------------------------------
// Prep: w2T[o][96] = padded transpose of w2 (72x256).
// Slot layout: 8 slots of 12 floats; slot js holds w2[js*9 + i][o] for i<9,
// zeros for i in 9..11 (pad keeps float4 alignment).
// ---------------------------------------------------------------------------
__global__ __launch_bounds__(256) void k_prep(const float* __restrict__ w2,
                                              float* __restrict__ w2T) {
    int idx = blockIdx.x * 256 + threadIdx.x;       // 0 .. 256*96-1
    if (idx >= OCN * 96) return;
    int o  = idx / 96;
    int r  = idx - o * 96;
    int js = r / 12;
    int i  = r - js * 12;
    float v = 0.f;
    if (i < 9) v = w2[(js * 9 + i) * OCN + o];      // j = js*9+i  (<=71)
    w2T[idx] = v;
}

// ---------------------------------------------------------------------------
// Copy x1 -> output 0 (identity output), float4 vectorized.
// ---------------------------------------------------------------------------
__global__ __launch_bounds__(256) void k_copy(const float4* __restrict__ src,
                                              float4* __restrict__ dst, int n4) {
    int i = blockIdx.x * 256 + threadIdx.x;
    if (i < n4) dst[i] = src[i];
}

// ---------------------------------------------------------------------------
// K1: offsets t[b][j][y][x].
// Per block: one 32-pixel row strip. Phase A computes xd (256 x 32) in LDS
// reading x straight from global (L1-resident working set, ~26 KB/block);
// Phase B does the 72x256 matvec with 9 accs/thread and weight prefetch.
// LDS = 32.8 KB -> 5 blocks/CU (vs 2 before).
// ---------------------------------------------------------------------------
__global__ __launch_bounds__(256, 4) void k_offsets(const float* __restrict__ x,
                                                    const float* __restrict__ w1,
                                                    const float* __restrict__ w2T,
                                                    const float* __restrict__ b2,
                                                    float* __restrict__ t_out) {
    __shared__ float lds_xd[OCN * SN];     // 32768 B
    const int x0  = blockIdx.x * SN;
    const int y   = blockIdx.y;
    const int b   = blockIdx.z;
    const int tid = threadIdx.x;
    const int px  = tid & 31;
    const int grp = tid >> 5;              // 0..7
    const float* xb = x + (size_t)b * CN * HWN;

    // Phase A: xd[o][px] = sum_k w1[o][k] * (x_nbr - x_center), straight from global
    {
        const int xcol = x0 + px;
        for (int i = 0; i < 8; ++i) {
            int c = grp * 8 + i;
            const float* xp = xb + (size_t)c * HWN;
            float ctr = xp[y * WN + xcol];
            float d[9];
            #pragma unroll
            for (int k = 0; k < 9; ++k) {
                int ky = k / 3;
                int kx = k - ky * 3;
                int yy = y - 1 + ky;
                int xx = xcol - 1 + kx;
                float v = 0.f;
                if ((unsigned)yy < (unsigned)HN && (unsigned)xx < (unsigned)WN)
                    v = xp[yy * WN + xx];
                d[k] = v - ctr;
            }
            #pragma unroll
            for (int e = 0; e < 4; ++e) {
                int o = c * 4 + e;
                const float* wr = w1 + o * 9;
                float acc = 0.f;
                #pragma unroll
                for (int k = 0; k < 9; ++k) acc += wr[k] * d[k];
                lds_xd[o * SN + px] = acc;
            }
        }
    }
    __syncthreads();

    // Phase B: t[j] = b2[j] + sum_o w2[j][o] * xd[o],  9 j's per thread
    {
        float acc[9];
        #pragma unroll
        for (int i = 0; i < 9; ++i) acc[i] = b2[grp * 9 + i];
        const float* wrowf = w2T + grp * 12;        // row base for this j-slot
        float4 wa = *(const float4*)(wrowf + 0);
        float4 wb = *(const float4*)(wrowf + 4);
        float  wc = wrowf[8];
        #pragma unroll 2
        for (int o = 0; o < OCN; ++o) {
            float xv = lds_xd[o * SN + px];
            int on = (o + 1 < OCN) ? (o + 1) : o;
            float4 na = *(const float4*)(wrowf + on * 96 + 0);
            float4 nb = *(const float4*)(wrowf + on * 96 + 4);
            float  nc = wrowf[on * 96 + 8];
            acc[0] += wa.x * xv; acc[1] += wa.y * xv; acc[2] += wa.z * xv; acc[3] += wa.w * xv;
            acc[4] += wb.x * xv; acc[5] += wb.y * xv; acc[6] += wb.z * xv; acc[7] += wb.w * xv;
            acc[8] += wc * xv;
            wa = na; wb = nb; wc = nc;
        }
        float* tb = t_out + (size_t)b * JCN * HWN + y * WN + x0 + px;
        #pragma unroll
        for (int i = 0; i < 9; ++i)
            tb[(size_t)(grp * 9 + i) * HWN] = acc[i];
    }
}

// ---------------------------------------------------------------------------
// K2: depthwise deformable conv + center correction -> y[b][c][h][w]
// ---------------------------------------------------------------------------
__device__ __forceinline__ float dsample(const float* __restrict__ p, int yi, int xi) {
    if ((unsigned)yi < (unsigned)HN && (unsigned)xi < (unsigned)WN)
        return p[yi * WN + xi];
    return 0.f;
}

__global__ __launch_bounds__(256) void k_deform(const float* __restrict__ x,
                                                const float* __restrict__ t_in,
                                                const float* __restrict__ wdef,
                                                float* __restrict__ y_out) {
    __shared__ float toff[JCN * SN];   // [j][px] 9.2 KB
    __shared__ float wk[CN * 9];
    __shared__ float wsum[CN];
    const int x0  = blockIdx.x * SN;
    const int yr  = blockIdx.y;
    const int b   = blockIdx.z;
    const int tid = threadIdx.x;

    const float* tb = t_in + (size_t)b * JCN * HWN + yr * WN + x0;
    for (int idx = tid; idx < JCN * SN; idx += 256) {
        int j  = idx >> 5;
        int px = idx & 31;
        toff[idx] = tb[(size_t)j * HWN + px];
    }
    for (int idx = tid; idx < CN * 9; idx += 256) wk[idx] = wdef[idx];
    if (tid < CN) {
        float s = 0.f;
        #pragma unroll
        for (int k = 0; k < 9; ++k) s += wdef[tid * 9 + k];
        wsum[tid] = s;
    }
    __syncthreads();

    const int px = tid & 31;
    const int cs = tid >> 5;
    for (int i = 0; i < 8; ++i) {
        int c = cs * 8 + i;
        int g = c >> 4;                           // deform group
        const float* xp = x + ((size_t)b * CN + c) * HWN;
        float xc  = xp[yr * WN + x0 + px];
        float acc = -xc * wsum[c];
        #pragma unroll
        for (int k = 0; k < 9; ++k) {
            int ky = k / 3;
            int kx = k - ky * 3;
            float dy = toff[((g * 9 + k) * 2 + 0) * SN + px];
            float dx = toff[((g * 9 + k) * 2 + 1) * SN + px];
            float py  = (float)(yr - 1 + ky) + dy;
            float pxf = (float)(x0 + px - 1 + kx) + dx;
            float y0f = floorf(py);
            float x0f = floorf(pxf);
            float wy = py - y0f;
            float wx = pxf - x0f;
            int yi = (int)y0f;
            int xi = (int)x0f;
            float v00 = dsample(xp, yi,     xi);
            float v01 = dsample(xp, yi,     xi + 1);
            float v10 = dsample(xp, yi + 1, xi);
            float v11 = dsample(xp, yi + 1, xi + 1);
            float bil = v00 * (1.f - wy) * (1.f - wx)
                      + v01 * (1.f - wy) * wx
                      + v10 * wy * (1.f - wx)
                      + v11 * wy * wx;
            acc += wk[c * 9 + k] * bil;
        }
        y_out[((size_t)b * CN + c) * HWN + yr * WN + x0 + px] = acc;
    }
}

// ---------------------------------------------------------------------------
// K3: m[b][o][h][w] = sum_c wout[o][c] * y[b][c][h][w]
// ---------------------------------------------------------------------------
__global__ __launch_bounds__(256) void k_final(const float* __restrict__ y_in,
                                               const float* __restrict__ wout,
                                               float* __restrict__ m_out) {
    __shared__ float lds_y[CN * SN];     // 8.2 KB
    __shared__ float ldsw[CN * CN];      // [c][o] 16.4 KB
    const int x0  = blockIdx.x * SN;
    const int yr  = blockIdx.y;
    const int b   = blockIdx.z;
    const int tid = threadIdx.x;

    for (int idx = tid; idx < CN * CN; idx += 256) {
        int c = idx >> 6;
        int o = idx & 63;
        ldsw[idx] = wout[o * CN + c];
    }
    for (int idx = tid; idx < CN * SN; idx += 256) {
        int c  = idx >> 5;
        int px = idx & 31;
        lds_y[idx] = y_in[((size_t)b * CN + c) * HWN + yr * WN + x0 + px];
    }
    __syncthreads();

    const int px = tid & 31;
    const int os = tid >> 5;                      // 0..7 -> 8 o's each
    float acc[8];
    #pragma unroll
    for (int i = 0; i < 8; ++i) acc[i] = 0.f;
    #pragma unroll 4
    for (int c = 0; c < CN; ++c) {
        float yv = lds_y[c * SN + px];
        const float4* wr = (const float4*)(ldsw + c * CN + os * 8);
        float4 wa = wr[0];
        float4 wb = wr[1];
        acc[0] += wa.x * yv; acc[1] += wa.y * yv; acc[2] += wa.z * yv; acc[3] += wa.w * yv;
        acc[4] += wb.x * yv; acc[5] += wb.y * yv; acc[6] += wb.z * yv; acc[7] += wb.w * yv;
    }
    #pragma unroll
    for (int i = 0; i < 8; ++i) {
        int o = os * 8 + i;
        m_out[((size_t)b * CN + o) * HWN + yr * WN + x0 + px] = acc[i];
    }
}

// ---------------------------------------------------------------------------
extern "C" void kernel_launch(void* const* d_in, const int* in_sizes, int n_in,
                              void* d_out, int out_size, void* d_ws, size_t ws_size,
                              hipStream_t stream) {
    const float* x1    = (const float*)d_in[0];   // 2*64*192*192
    const float* w_off1 = (const float*)d_in[1];  // 256*9
    const float* w_off2 = (const float*)d_in[2];  // 72*256
    const float* b_off2 = (const float*)d_in[3];  // 72
    const float* w_def = (const float*)d_in[4];   // 64*9
    const float* w_out = (const float*)d_in[5];   // 64*64

    float* out = (float*)d_out;
    const size_t n_x = (size_t)BN * CN * HWN;     // 4718592
    float* out_x1 = out;                          // output 0: x1 copy
    float* out_m  = out + n_x;                    // output 1: m

    // Workspace layout (floats)
    float* ws   = (float*)d_ws;
    float* w2T  = ws;                             // 256*96 = 24576
    float* t_ws = ws + 24576;                     // 2*72*36864 = 5308416
    float* y_ws = t_ws + (size_t)BN * JCN * HWN;  // 2*64*36864 = 4718592

    dim3 grid(WN / SN, HN, BN);                   // (6, 192, 2)
    dim3 blk(256);

    k_prep<<<dim3((OCN * 96 + 255) / 256), blk, 0, stream>>>(w_off2, w2T);
    k_copy<<<dim3((int)(n_x / 4 + 255) / 256), blk, 0, stream>>>(
        (const float4*)x1, (float4*)out_x1, (int)(n_x / 4));
    k_offsets<<<grid, blk, 0, stream>>>(x1, w_off1, w2T, b_off2, t_ws);
    k_deform<<<grid, blk, 0, stream>>>(x1, t_ws, w_def, y_ws);
    k_final<<<grid, blk, 0, stream>>>(y_ws, w_out, out_m);
}

// Round 3
// 355.169 us; speedup vs baseline: 1.4260x; 1.2434x over previous
//
#include <hip/hip_runtime.h>

// Problem constants (B=2, C=64, H=W=192, EXP=4, DG=4, K=3)
#define BN   2
#define CN   64
#define HN   192
#define WN   192
#define HWN  36864          // 192*192
#define OCN  256            // EXP*C
#define JCN  72             // DG*2*9
#define SNO  64             // pixel strip for k_offsets
#define SN   32             // pixel strip for deform/final
#define JW   18             // j's per wave in k_offsets
#define WSLOT 20            // padded weight slot (18 real + 2 zero)

// ---------------------------------------------------------------------------
// Prep: w2Tw[w][o][20]: slot for wave w holds w2[w*18+i][o], i<18; pad 0.
// ---------------------------------------------------------------------------
__global__ __launch_bounds__(256) void k_prep(const float* __restrict__ w2,
                                              float* __restrict__ w2Tw) {
    int idx = blockIdx.x * 256 + threadIdx.x;      // 0 .. 4*256*20-1
    if (idx >= 4 * OCN * WSLOT) return;
    int w = idx / (OCN * WSLOT);
    int r = idx - w * (OCN * WSLOT);
    int o = r / WSLOT;
    int i = r - o * WSLOT;
    float v = 0.f;
    if (i < JW) v = w2[(w * JW + i) * OCN + o];
    w2Tw[idx] = v;
}

// ---------------------------------------------------------------------------
// K1: offsets t[b][j][y][x] + fused x1 copy.
// K chunked 4x64: double-buffered 64x64 xd tile in LDS; per chunk: issue next
// chunk's x loads -> accumulate current chunk (FMAs hide load latency) ->
// convert+write next tile -> barrier. Weight rows are wave-uniform.
// ---------------------------------------------------------------------------
__global__ __launch_bounds__(256, 4) void k_offsets(const float* __restrict__ x,
                                                    const float* __restrict__ w1,
                                                    const float* __restrict__ w2Tw,
                                                    const float* __restrict__ b2,
                                                    float* __restrict__ t_out,
                                                    float* __restrict__ x_copy) {
    __shared__ float buf[2][64 * SNO];             // 2 x 16 KB
    const int x0  = blockIdx.x * SNO;
    const int y   = blockIdx.y;
    const int b   = blockIdx.z;
    const int tid = threadIdx.x;
    const int px  = tid & 63;
    const int wv  = __builtin_amdgcn_readfirstlane(tid >> 6);   // wave id 0..3
    const int xcol = x0 + px;
    const float* xb    = x + (size_t)b * CN * HWN;
    const float* wbase = w2Tw + (size_t)wv * OCN * WSLOT;

    float acc[WSLOT];
    #pragma unroll
    for (int i = 0; i < WSLOT; ++i) acc[i] = 0.f;
    #pragma unroll
    for (int i = 0; i < JW; ++i) acc[i] = b2[wv * JW + i];

    float ld[4][9];                                 // next chunk's raw x taps

    // ---- load chunk 0 taps ----
    #pragma unroll
    for (int cc = 0; cc < 4; ++cc) {
        int c = cc * 4 + wv;                        // chunk 0 channels
        const float* xp = xb + (size_t)c * HWN;
        #pragma unroll
        for (int k = 0; k < 9; ++k) {
            int ky = k / 3, kx = k - 3 * ky;
            int yy = y - 1 + ky, xx = xcol - 1 + kx;
            float v = 0.f;
            if ((unsigned)yy < (unsigned)HN && (unsigned)xx < (unsigned)WN)
                v = xp[yy * WN + xx];
            ld[cc][k] = v;
        }
    }
    // ---- convert+write chunk 0 ----
    {
        float* bw = buf[0];
        #pragma unroll
        for (int cc = 0; cc < 4; ++cc) {
            int c = cc * 4 + wv;
            float ctr = ld[cc][4];
            x_copy[((size_t)b * CN + c) * HWN + y * WN + xcol] = ctr;
            const float* wr = w1 + (size_t)(c * 4) * 9;
            float d[9];
            #pragma unroll
            for (int k = 0; k < 9; ++k) d[k] = ld[cc][k] - ctr;
            #pragma unroll
            for (int e = 0; e < 4; ++e) {
                float a = 0.f;
                #pragma unroll
                for (int k = 0; k < 9; ++k)
                    if (k != 4) a += wr[e * 9 + k] * d[k];
                int ol = (cc * 4 + wv) * 4 + e;
                bw[ol * SNO + px] = a;
            }
        }
    }
    __syncthreads();

    for (int q = 0; q < 4; ++q) {
        // ---- issue next chunk's loads (latency overlapped by accumulate) ----
        if (q < 3) {
            #pragma unroll
            for (int cc = 0; cc < 4; ++cc) {
                int c = (q + 1) * 16 + cc * 4 + wv;
                const float* xp = xb + (size_t)c * HWN;
                #pragma unroll
                for (int k = 0; k < 9; ++k) {
                    int ky = k / 3, kx = k - 3 * ky;
                    int yy = y - 1 + ky, xx = xcol - 1 + kx;
                    float v = 0.f;
                    if ((unsigned)yy < (unsigned)HN && (unsigned)xx < (unsigned)WN)
                        v = xp[yy * WN + xx];
                    ld[cc][k] = v;
                }
            }
        }
        // ---- accumulate chunk q ----
        {
            const float* bq = buf[q & 1];
            #pragma unroll 2
            for (int ol = 0; ol < 64; ++ol) {
                float xv = bq[ol * SNO + px];
                const float4* wr = (const float4*)(wbase + (size_t)(q * 64 + ol) * WSLOT);
                float4 w0 = wr[0], w1v = wr[1], w2v = wr[2], w3v = wr[3], w4v = wr[4];
                acc[0]  += w0.x  * xv; acc[1]  += w0.y  * xv; acc[2]  += w0.z  * xv; acc[3]  += w0.w  * xv;
                acc[4]  += w1v.x * xv; acc[5]  += w1v.y * xv; acc[6]  += w1v.z * xv; acc[7]  += w1v.w * xv;
                acc[8]  += w2v.x * xv; acc[9]  += w2v.y * xv; acc[10] += w2v.z * xv; acc[11] += w2v.w * xv;
                acc[12] += w3v.x * xv; acc[13] += w3v.y * xv; acc[14] += w3v.z * xv; acc[15] += w3v.w * xv;
                acc[16] += w4v.x * xv; acc[17] += w4v.y * xv; acc[18] += w4v.z * xv; acc[19] += w4v.w * xv;
            }
        }
        // ---- convert+write next chunk ----
        if (q < 3) {
            float* bw = buf[(q + 1) & 1];
            #pragma unroll
            for (int cc = 0; cc < 4; ++cc) {
                int c = (q + 1) * 16 + cc * 4 + wv;
                float ctr = ld[cc][4];
                x_copy[((size_t)b * CN + c) * HWN + y * WN + xcol] = ctr;
                const float* wr = w1 + (size_t)(c * 4) * 9;
                float d[9];
                #pragma unroll
                for (int k = 0; k < 9; ++k) d[k] = ld[cc][k] - ctr;
                #pragma unroll
                for (int e = 0; e < 4; ++e) {
                    float a = 0.f;
                    #pragma unroll
                    for (int k = 0; k < 9; ++k)
                        if (k != 4) a += wr[e * 9 + k] * d[k];
                    int ol = (cc * 4 + wv) * 4 + e;
                    bw[ol * SNO + px] = a;
                }
            }
        }
        __syncthreads();
    }

    // ---- store t: j = wv*18 + i ----
    float* tb = t_out + (size_t)b * JCN * HWN + y * WN + xcol;
    #pragma unroll
    for (int i = 0; i < JW; ++i)
        tb[(size_t)(wv * JW + i) * HWN] = acc[i];
}

// ---------------------------------------------------------------------------
// K2: depthwise deformable conv + center correction -> y[b][c][h][w]
// ---------------------------------------------------------------------------
__device__ __forceinline__ float dsample(const float* __restrict__ p, int yi, int xi) {
    if ((unsigned)yi < (unsigned)HN && (unsigned)xi < (unsigned)WN)
        return p[yi * WN + xi];
    return 0.f;
}

__global__ __launch_bounds__(256) void k_deform(const float* __restrict__ x,
                                                const float* __restrict__ t_in,
                                                const float* __restrict__ wdef,
                                                float* __restrict__ y_out) {
    __shared__ float toff[JCN * SN];   // [j][px] 9.2 KB
    __shared__ float wk[CN * 9];
    __shared__ float wsum[CN];
    const int x0  = blockIdx.x * SN;
    const int yr  = blockIdx.y;
    const int b   = blockIdx.z;
    const int tid = threadIdx.x;

    const float* tb = t_in + (size_t)b * JCN * HWN + yr * WN + x0;
    for (int idx = tid; idx < JCN * SN; idx += 256) {
        int j  = idx >> 5;
        int px = idx & 31;
        toff[idx] = tb[(size_t)j * HWN + px];
    }
    for (int idx = tid; idx < CN * 9; idx += 256) wk[idx] = wdef[idx];
    if (tid < CN) {
        float s = 0.f;
        #pragma unroll
        for (int k = 0; k < 9; ++k) s += wdef[tid * 9 + k];
        wsum[tid] = s;
    }
    __syncthreads();

    const int px = tid & 31;
    const int cs = tid >> 5;
    for (int i = 0; i < 8; ++i) {
        int c = cs * 8 + i;
        int g = c >> 4;                           // deform group
        const float* xp = x + ((size_t)b * CN + c) * HWN;
        float xc  = xp[yr * WN + x0 + px];
        float acc = -xc * wsum[c];
        #pragma unroll
        for (int k = 0; k < 9; ++k) {
            int ky = k / 3;
            int kx = k - ky * 3;
            float dy = toff[((g * 9 + k) * 2 + 0) * SN + px];
            float dx = toff[((g * 9 + k) * 2 + 1) * SN + px];
            float py  = (float)(yr - 1 + ky) + dy;
            float pxf = (float)(x0 + px - 1 + kx) + dx;
            float y0f = floorf(py);
            float x0f = floorf(pxf);
            float wy = py - y0f;
            float wx = pxf - x0f;
            int yi = (int)y0f;
            int xi = (int)x0f;
            float v00 = dsample(xp, yi,     xi);
            float v01 = dsample(xp, yi,     xi + 1);
            float v10 = dsample(xp, yi + 1, xi);
            float v11 = dsample(xp, yi + 1, xi + 1);
            float bil = v00 * (1.f - wy) * (1.f - wx)
                      + v01 * (1.f - wy) * wx
                      + v10 * wy * (1.f - wx)
                      + v11 * wy * wx;
            acc += wk[c * 9 + k] * bil;
        }
        y_out[((size_t)b * CN + c) * HWN + yr * WN + x0 + px] = acc;
    }
}

// ---------------------------------------------------------------------------
// K3: m[b][o][h][w] = sum_c wout[o][c] * y[b][c][h][w]
// ---------------------------------------------------------------------------
__global__ __launch_bounds__(256) void k_final(const float* __restrict__ y_in,
                                               const float* __restrict__ wout,
                                               float* __restrict__ m_out) {
    __shared__ float lds_y[CN * SN];     // 8.2 KB
    __shared__ float ldsw[CN * CN];      // [c][o] 16.4 KB
    const int x0  = blockIdx.x * SN;
    const int yr  = blockIdx.y;
    const int b   = blockIdx.z;
    const int tid = threadIdx.x;

    for (int idx = tid; idx < CN * CN; idx += 256) {
        int c = idx >> 6;
        int o = idx & 63;
        ldsw[idx] = wout[o * CN + c];
    }
    for (int idx = tid; idx < CN * SN; idx += 256) {
        int c  = idx >> 5;
        int px = idx & 31;
        lds_y[idx] = y_in[((size_t)b * CN + c) * HWN + yr * WN + x0 + px];
    }
    __syncthreads();

    const int px = tid & 31;
    const int os = tid >> 5;                      // 0..7 -> 8 o's each
    float acc[8];
    #pragma unroll
    for (int i = 0; i < 8; ++i) acc[i] = 0.f;
    #pragma unroll 4
    for (int c = 0; c < CN; ++c) {
        float yv = lds_y[c * SN + px];
        const float4* wr = (const float4*)(ldsw + c * CN + os * 8);
        float4 wa = wr[0];
        float4 wb = wr[1];
        acc[0] += wa.x * yv; acc[1] += wa.y * yv; acc[2] += wa.z * yv; acc[3] += wa.w * yv;
        acc[4] += wb.x * yv; acc[5] += wb.y * yv; acc[6] += wb.z * yv; acc[7] += wb.w * yv;
    }
    #pragma unroll
    for (int i = 0; i < 8; ++i) {
        int o = os * 8 + i;
        m_out[((size_t)b * CN + o) * HWN + yr * WN + x0 + px] = acc[i];
    }
}

// ---------------------------------------------------------------------------
extern "C" void kernel_launch(void* const* d_in, const int* in_sizes, int n_in,
                              void* d_out, int out_size, void* d_ws, size_t ws_size,
                              hipStream_t stream) {
    const float* x1    = (const float*)d_in[0];   // 2*64*192*192
    const float* w_off1 = (const float*)d_in[1];  // 256*9
    const float* w_off2 = (const float*)d_in[2];  // 72*256
    const float* b_off2 = (const float*)d_in[3];  // 72
    const float* w_def = (const float*)d_in[4];   // 64*9
    const float* w_out = (const float*)d_in[5];   // 64*64

    float* out = (float*)d_out;
    const size_t n_x = (size_t)BN * CN * HWN;     // 4718592
    float* out_x1 = out;                          // output 0: x1 copy
    float* out_m  = out + n_x;                    // output 1: m

    // Workspace layout (floats)
    float* ws   = (float*)d_ws;
    float* w2Tw = ws;                             // 4*256*20 = 20480
    float* t_ws = ws + 20480;                     // 2*72*36864 = 5308416
    float* y_ws = t_ws + (size_t)BN * JCN * HWN;  // 2*64*36864 = 4718592

    dim3 blk(256);

    k_prep<<<dim3((4 * OCN * WSLOT + 255) / 256), blk, 0, stream>>>(w_off2, w2Tw);
    k_offsets<<<dim3(WN / SNO, HN, BN), blk, 0, stream>>>(x1, w_off1, w2Tw, b_off2,
                                                          t_ws, out_x1);
    k_deform<<<dim3(WN / SN, HN, BN), blk, 0, stream>>>(x1, t_ws, w_def, y_ws);
    k_final<<<dim3(WN / SN, HN, BN), blk, 0, stream>>>(y_ws, w_out, out_m);
}

// Round 4
// 297.760 us; speedup vs baseline: 1.7009x; 1.1928x over previous
//
#include <hip/hip_runtime.h>

// Problem constants (B=2, C=64, H=W=192, EXP=4, DG=4, K=3)
#define BN   2
#define CN   64
#define HN   192
#define WN   192
#define HWN  36864          // 192*192
#define OCN  256            // EXP*C
#define JCN  72             // DG*2*9
#define SNO  64             // pixel strip for k_offsets
#define SN   32             // pixel strip for deform/final
#define JW   18             // j's per wave in k_offsets
#define WSLOT 20            // padded weight slot (18 real + 2 zero)

// k_deform tile geometry
#define DROWS 8             // output rows per block
#define XH    18            // staged x rows (halo 5 top / 4 bottom + corner)
#define XW    48            // staged x cols (halo 8 left / 7 right + corner)
#define XRT   5             // row halo top
#define XCL   8             // col halo left

// ---------------------------------------------------------------------------
// Prep: w2Tw[w][o][20]: slot for wave w holds w2[w*18+i][o], i<18; pad 0.
// ---------------------------------------------------------------------------
__global__ __launch_bounds__(256) void k_prep(const float* __restrict__ w2,
                                              float* __restrict__ w2Tw) {
    int idx = blockIdx.x * 256 + threadIdx.x;      // 0 .. 4*256*20-1
    if (idx >= 4 * OCN * WSLOT) return;
    int w = idx / (OCN * WSLOT);
    int r = idx - w * (OCN * WSLOT);
    int o = r / WSLOT;
    int i = r - o * WSLOT;
    float v = 0.f;
    if (i < JW) v = w2[(w * JW + i) * OCN + o];
    w2Tw[idx] = v;
}

// ---------------------------------------------------------------------------
// K1: offsets t[b][j][y][x] + fused x1 copy. (unchanged from round 3)
// ---------------------------------------------------------------------------
__global__ __launch_bounds__(256, 4) void k_offsets(const float* __restrict__ x,
                                                    const float* __restrict__ w1,
                                                    const float* __restrict__ w2Tw,
                                                    const float* __restrict__ b2,
                                                    float* __restrict__ t_out,
                                                    float* __restrict__ x_copy) {
    __shared__ float buf[2][64 * SNO];             // 2 x 16 KB
    const int x0  = blockIdx.x * SNO;
    const int y   = blockIdx.y;
    const int b   = blockIdx.z;
    const int tid = threadIdx.x;
    const int px  = tid & 63;
    const int wv  = __builtin_amdgcn_readfirstlane(tid >> 6);   // wave id 0..3
    const int xcol = x0 + px;
    const float* xb    = x + (size_t)b * CN * HWN;
    const float* wbase = w2Tw + (size_t)wv * OCN * WSLOT;

    float acc[WSLOT];
    #pragma unroll
    for (int i = 0; i < WSLOT; ++i) acc[i] = 0.f;
    #pragma unroll
    for (int i = 0; i < JW; ++i) acc[i] = b2[wv * JW + i];

    float ld[4][9];                                 // next chunk's raw x taps

    #pragma unroll
    for (int cc = 0; cc < 4; ++cc) {
        int c = cc * 4 + wv;
        const float* xp = xb + (size_t)c * HWN;
        #pragma unroll
        for (int k = 0; k < 9; ++k) {
            int ky = k / 3, kx = k - 3 * ky;
            int yy = y - 1 + ky, xx = xcol - 1 + kx;
            float v = 0.f;
            if ((unsigned)yy < (unsigned)HN && (unsigned)xx < (unsigned)WN)
                v = xp[yy * WN + xx];
            ld[cc][k] = v;
        }
    }
    {
        float* bw = buf[0];
        #pragma unroll
        for (int cc = 0; cc < 4; ++cc) {
            int c = cc * 4 + wv;
            float ctr = ld[cc][4];
            x_copy[((size_t)b * CN + c) * HWN + y * WN + xcol] = ctr;
            const float* wr = w1 + (size_t)(c * 4) * 9;
            float d[9];
            #pragma unroll
            for (int k = 0; k < 9; ++k) d[k] = ld[cc][k] - ctr;
            #pragma unroll
            for (int e = 0; e < 4; ++e) {
                float a = 0.f;
                #pragma unroll
                for (int k = 0; k < 9; ++k)
                    if (k != 4) a += wr[e * 9 + k] * d[k];
                int ol = (cc * 4 + wv) * 4 + e;
                bw[ol * SNO + px] = a;
            }
        }
    }
    __syncthreads();

    for (int q = 0; q < 4; ++q) {
        if (q < 3) {
            #pragma unroll
            for (int cc = 0; cc < 4; ++cc) {
                int c = (q + 1) * 16 + cc * 4 + wv;
                const float* xp = xb + (size_t)c * HWN;
                #pragma unroll
                for (int k = 0; k < 9; ++k) {
                    int ky = k / 3, kx = k - 3 * ky;
                    int yy = y - 1 + ky, xx = xcol - 1 + kx;
                    float v = 0.f;
                    if ((unsigned)yy < (unsigned)HN && (unsigned)xx < (unsigned)WN)
                        v = xp[yy * WN + xx];
                    ld[cc][k] = v;
                }
            }
        }
        {
            const float* bq = buf[q & 1];
            #pragma unroll 2
            for (int ol = 0; ol < 64; ++ol) {
                float xv = bq[ol * SNO + px];
                const float4* wr = (const float4*)(wbase + (size_t)(q * 64 + ol) * WSLOT);
                float4 w0 = wr[0], w1v = wr[1], w2v = wr[2], w3v = wr[3], w4v = wr[4];
                acc[0]  += w0.x  * xv; acc[1]  += w0.y  * xv; acc[2]  += w0.z  * xv; acc[3]  += w0.w  * xv;
                acc[4]  += w1v.x * xv; acc[5]  += w1v.y * xv; acc[6]  += w1v.z * xv; acc[7]  += w1v.w * xv;
                acc[8]  += w2v.x * xv; acc[9]  += w2v.y * xv; acc[10] += w2v.z * xv; acc[11] += w2v.w * xv;
                acc[12] += w3v.x * xv; acc[13] += w3v.y * xv; acc[14] += w3v.z * xv; acc[15] += w3v.w * xv;
                acc[16] += w4v.x * xv; acc[17] += w4v.y * xv; acc[18] += w4v.z * xv; acc[19] += w4v.w * xv;
            }
        }
        if (q < 3) {
            float* bw = buf[(q + 1) & 1];
            #pragma unroll
            for (int cc = 0; cc < 4; ++cc) {
                int c = (q + 1) * 16 + cc * 4 + wv;
                float ctr = ld[cc][4];
                x_copy[((size_t)b * CN + c) * HWN + y * WN + xcol] = ctr;
                const float* wr = w1 + (size_t)(c * 4) * 9;
                float d[9];
                #pragma unroll
                for (int k = 0; k < 9; ++k) d[k] = ld[cc][k] - ctr;
                #pragma unroll
                for (int e = 0; e < 4; ++e) {
                    float a = 0.f;
                    #pragma unroll
                    for (int k = 0; k < 9; ++k)
                        if (k != 4) a += wr[e * 9 + k] * d[k];
                    int ol = (cc * 4 + wv) * 4 + e;
                    bw[ol * SNO + px] = a;
                }
            }
        }
        __syncthreads();
    }

    float* tb = t_out + (size_t)b * JCN * HWN + y * WN + xcol;
    #pragma unroll
    for (int i = 0; i < JW; ++i)
        tb[(size_t)(wv * JW + i) * HWN] = acc[i];
}

// ---------------------------------------------------------------------------
// K2: depthwise deformable conv, LDS-staged 2D tile version.
// Block: 8 channels (one deform group) x (8 rows x 32 cols) output tile.
// x window 8x18x48 + 18 offset planes staged in LDS; bilinear reads LDS;
// rare out-of-window taps fall back to guarded global loads.
// ---------------------------------------------------------------------------
__device__ __forceinline__ float dsample(const float* __restrict__ p, int yi, int xi) {
    if ((unsigned)yi < (unsigned)HN && (unsigned)xi < (unsigned)WN)
        return p[yi * WN + xi];
    return 0.f;
}

__global__ __launch_bounds__(256, 3) void k_deform(const float* __restrict__ x,
                                                   const float* __restrict__ t_in,
                                                   const float* __restrict__ wdef,
                                                   float* __restrict__ y_out) {
    __shared__ float xs[8 * XH * XW];                 // 27648 B
    __shared__ float ts[9 * DROWS * 32 * 2];          // 18432 B  [k][r][px][dy|dx]
    const int x0   = blockIdx.x * SN;
    const int yr0  = blockIdx.y * DROWS;
    const int zz   = blockIdx.z;
    const int b    = zz >> 3;
    const int chunk = zz & 7;                         // 8-channel chunk
    const int g    = chunk >> 1;                      // deform group
    const int tid  = threadIdx.x;
    const int grp  = tid >> 5;                        // channel within chunk
    const int px   = tid & 31;
    const int c    = chunk * 8 + grp;
    const int row_lo = yr0 - XRT;
    const int col_lo = x0 - XCL;
    const float* xb = x + (size_t)b * CN * HWN;

    // stage x window (zero-filled outside the image = valid-mask semantics)
    for (int idx = tid; idx < 8 * XH * XW; idx += 256) {
        int cc  = idx / (XH * XW);
        int rem = idx - cc * (XH * XW);
        int r   = rem / XW;
        int col = rem - r * XW;
        int yy  = row_lo + r;
        int xx  = col_lo + col;
        float v = 0.f;
        if ((unsigned)yy < (unsigned)HN && (unsigned)xx < (unsigned)WN)
            v = xb[(size_t)(chunk * 8 + cc) * HWN + yy * WN + xx];
        xs[idx] = v;
    }
    // stage offsets for this group's tile, interleaved (dy,dx)
    const float* tbp = t_in + ((size_t)b * JCN + g * 18) * HWN;
    for (int idx = tid; idx < 18 * DROWS * 32; idx += 256) {
        int j   = idx / (DROWS * 32);
        int rem = idx - j * (DROWS * 32);
        int r   = rem >> 5;
        int cl  = rem & 31;
        float v = tbp[(size_t)j * HWN + (yr0 + r) * WN + x0 + cl];
        int k = j >> 1, comp = j & 1;
        ts[((k * DROWS + r) * 32 + cl) * 2 + comp] = v;
    }
    __syncthreads();

    float wk[9];
    float wsum = 0.f;
    #pragma unroll
    for (int k = 0; k < 9; ++k) { wk[k] = wdef[c * 9 + k]; wsum += wk[k]; }

    const float* xcp = xs + grp * (XH * XW);
    const float* xg  = xb + (size_t)c * HWN;          // fallback plane

    float acc[DROWS];
    #pragma unroll
    for (int r = 0; r < DROWS; ++r)
        acc[r] = -xcp[(XRT + r) * XW + XCL + px] * wsum;

    for (int k = 0; k < 9; ++k) {
        const int ky = k / 3, kx = k - 3 * ky;
        #pragma unroll
        for (int r = 0; r < DROWS; ++r) {
            float2 d = *(const float2*)&ts[((k * DROWS + r) * 32 + px) * 2];
            float py  = (float)(yr0 + r - 1 + ky) + d.x;
            float pxf = (float)(x0 + px - 1 + kx) + d.y;
            float y0f = floorf(py);
            float x0f = floorf(pxf);
            float wy = py - y0f;
            float wx = pxf - x0f;
            int yi = (int)y0f;
            int xi = (int)x0f;
            int ry = yi - row_lo;
            int rx = xi - col_lo;
            float v00, v01, v10, v11;
            if ((unsigned)ry < (XH - 1) && (unsigned)rx < (XW - 1)) {
                const float* p = xcp + ry * XW + rx;
                v00 = p[0]; v01 = p[1]; v10 = p[XW]; v11 = p[XW + 1];
            } else {
                v00 = dsample(xg, yi,     xi);
                v01 = dsample(xg, yi,     xi + 1);
                v10 = dsample(xg, yi + 1, xi);
                v11 = dsample(xg, yi + 1, xi + 1);
            }
            float bil = v00 * (1.f - wy) * (1.f - wx)
                      + v01 * (1.f - wy) * wx
                      + v10 * wy * (1.f - wx)
                      + v11 * wy * wx;
            acc[r] += wk[k] * bil;
        }
    }
    #pragma unroll
    for (int r = 0; r < DROWS; ++r)
        y_out[((size_t)b * CN + c) * HWN + (yr0 + r) * WN + x0 + px] = acc[r];
}

// ---------------------------------------------------------------------------
// K3: m[b][o][h][w] = sum_c wout[o][c] * y[b][c][h][w]
// ---------------------------------------------------------------------------
__global__ __launch_bounds__(256) void k_final(const float* __restrict__ y_in,
                                               const float* __restrict__ wout,
                                               float* __restrict__ m_out) {
    __shared__ float lds_y[CN * SN];     // 8.2 KB
    __shared__ float ldsw[CN * CN];      // [c][o] 16.4 KB
    const int x0  = blockIdx.x * SN;
    const int yr  = blockIdx.y;
    const int b   = blockIdx.z;
    const int tid = threadIdx.x;

    for (int idx = tid; idx < CN * CN; idx += 256) {
        int c = idx >> 6;
        int o = idx & 63;
        ldsw[idx] = wout[o * CN + c];
    }
    for (int idx = tid; idx < CN * SN; idx += 256) {
        int c  = idx >> 5;
        int px = idx & 31;
        lds_y[idx] = y_in[((size_t)b * CN + c) * HWN + yr * WN + x0 + px];
    }
    __syncthreads();

    const int px = tid & 31;
    const int os = tid >> 5;                      // 0..7 -> 8 o's each
    float acc[8];
    #pragma unroll
    for (int i = 0; i < 8; ++i) acc[i] = 0.f;
    #pragma unroll 4
    for (int c = 0; c < CN; ++c) {
        float yv = lds_y[c * SN + px];
        const float4* wr = (const float4*)(ldsw + c * CN + os * 8);
        float4 wa = wr[0];
        float4 wb = wr[1];
        acc[0] += wa.x * yv; acc[1] += wa.y * yv; acc[2] += wa.z * yv; acc[3] += wa.w * yv;
        acc[4] += wb.x * yv; acc[5] += wb.y * yv; acc[6] += wb.z * yv; acc[7] += wb.w * yv;
    }
    #pragma unroll
    for (int i = 0; i < 8; ++i) {
        int o = os * 8 + i;
        m_out[((size_t)b * CN + o) * HWN + yr * WN + x0 + px] = acc[i];
    }
}

// ---------------------------------------------------------------------------
extern "C" void kernel_launch(void* const* d_in, const int* in_sizes, int n_in,
                              void* d_out, int out_size, void* d_ws, size_t ws_size,
                              hipStream_t stream) {
    const float* x1    = (const float*)d_in[0];   // 2*64*192*192
    const float* w_off1 = (const float*)d_in[1];  // 256*9
    const float* w_off2 = (const float*)d_in[2];  // 72*256
    const float* b_off2 = (const float*)d_in[3];  // 72
    const float* w_def = (const float*)d_in[4];   // 64*9
    const float* w_out = (const float*)d_in[5];   // 64*64

    float* out = (float*)d_out;
    const size_t n_x = (size_t)BN * CN * HWN;     // 4718592
    float* out_x1 = out;                          // output 0: x1 copy
    float* out_m  = out + n_x;                    // output 1: m

    // Workspace layout (floats)
    float* ws   = (float*)d_ws;
    float* w2Tw = ws;                             // 4*256*20 = 20480
    float* t_ws = ws + 20480;                     // 2*72*36864 = 5308416
    float* y_ws = t_ws + (size_t)BN * JCN * HWN;  // 2*64*36864 = 4718592

    dim3 blk(256);

    k_prep<<<dim3((4 * OCN * WSLOT + 255) / 256), blk, 0, stream>>>(w_off2, w2Tw);
    k_offsets<<<dim3(WN / SNO, HN, BN), blk, 0, stream>>>(x1, w_off1, w2Tw, b_off2,
                                                          t_ws, out_x1);
    k_deform<<<dim3(WN / SN, HN / DROWS, BN * 8), blk, 0, stream>>>(x1, t_ws, w_def, y_ws);
    k_final<<<dim3(WN / SN, HN, BN), blk, 0, stream>>>(y_ws, w_out, out_m);
}

// Round 5
// 224.481 us; speedup vs baseline: 2.2561x; 1.3264x over previous
//
#include <hip/hip_runtime.h>

// Problem constants (B=2, C=64, H=W=192, EXP=4, DG=4, K=3)
#define BN   2
#define CN   64
#define HN   192
#define WN   192
#define HWN  36864          // 192*192
#define OCN  256            // EXP*C
#define JCN  72             // DG*2*9
#define SN   32             // pixel strip for deform

// k_deform tile geometry
#define DROWS 8             // output rows per block
#define XH    18            // staged x rows
#define XW    48            // staged x cols
#define XRT   5             // row halo top
#define XCL   8             // col halo left

// k_offsets MFMA geometry
#define PITCH 264           // bf16 pitch of xd row (256 + 8 pad)

typedef __attribute__((ext_vector_type(8))) short bf16x8;
typedef __attribute__((ext_vector_type(4))) float f32x4;

__device__ __forceinline__ unsigned short f2bf(float f) {
    union { float f; unsigned u; } v; v.f = f;
    unsigned r = v.u + 0x7fffu + ((v.u >> 16) & 1u);
    return (unsigned short)(r >> 16);
}

// ---------------------------------------------------------------------------
// Prep:
//  job 1: w2mf = w2 (72x256) in bf16, swizzled to MFMA A-fragment order:
//         w2mf[((tm*8+s)*64 + lane)*8 + j] = bf16(w2[tm*16+(lane&15)][s*32+(lane>>4)*8+j])
//         (rows 72..79 zero-padded). 20480 elems = 40 KB, L1-resident.
//  job 2: w_outT[c*64+o] = w_out[o*64+c]  (4096 floats)
// ---------------------------------------------------------------------------
__global__ __launch_bounds__(256) void k_prep(const float* __restrict__ w2,
                                              const float* __restrict__ w_out,
                                              unsigned short* __restrict__ w2mf,
                                              float* __restrict__ w_outT) {
    int idx = blockIdx.x * 256 + threadIdx.x;
    if (idx < 20480) {
        int j  = idx & 7;
        int l  = (idx >> 3) & 63;
        int ts = idx >> 9;             // tm*8+s, 0..39
        int tm = ts >> 3, s = ts & 7;
        int jrow = tm * 16 + (l & 15);
        int k    = s * 32 + (l >> 4) * 8 + j;
        float v = (jrow < JCN) ? w2[jrow * OCN + k] : 0.f;
        w2mf[idx] = f2bf(v);
    } else if (idx < 24576) {
        int r = idx - 20480;
        int c = r >> 6, o = r & 63;
        w_outT[r] = w_out[o * CN + c];
    }
}

// ---------------------------------------------------------------------------
// K1: offsets t[b][j][y][x] + fused x1 copy.  MFMA version.
// Phase A: compute xd (256 o x 64 px) in bf16 into LDS [px][o] (+8 pad),
//          4 software-pipelined rounds of 4 channels/thread, fp32 math.
// Phase B: t[80pad x 64] = w2[80x256] . xd[256x64] via mfma_f32_16x16x32_bf16.
//          Wave w owns n-slab px = w*16..+16; 5 M-tiles; B-frags reused.
// ---------------------------------------------------------------------------
__global__ __launch_bounds__(256, 4) void k_offsets(const float* __restrict__ x,
                                                    const float* __restrict__ w1,
                                                    const unsigned short* __restrict__ w2mf,
                                                    const float* __restrict__ b2,
                                                    float* __restrict__ t_out,
                                                    float* __restrict__ x_copy) {
    __shared__ unsigned short xd[64 * PITCH];       // 33792 B
    const int x0  = blockIdx.x * 64;
    const int y   = blockIdx.y;
    const int b   = blockIdx.z;
    const int tid = threadIdx.x;
    const int px  = tid & 63;
    const int wv  = tid >> 6;                       // wave id 0..3
    const int xcol = x0 + px;
    const float* xb = x + (size_t)b * CN * HWN;

    auto load_round = [&](int r, float (*ld)[9]) {
        #pragma unroll
        for (int cc = 0; cc < 4; ++cc) {
            int c = r * 16 + cc * 4 + wv;
            const float* xp = xb + (size_t)c * HWN;
            #pragma unroll
            for (int k = 0; k < 9; ++k) {
                int ky = k / 3, kx = k - 3 * ky;
                int yy = y - 1 + ky, xx = xcol - 1 + kx;
                float v = 0.f;
                if ((unsigned)yy < (unsigned)HN && (unsigned)xx < (unsigned)WN)
                    v = xp[yy * WN + xx];
                ld[cc][k] = v;
            }
        }
    };
    auto conv_round = [&](int r, float (*ld)[9]) {
        #pragma unroll
        for (int cc = 0; cc < 4; ++cc) {
            int c = r * 16 + cc * 4 + wv;
            float ctr = ld[cc][4];
            x_copy[((size_t)b * CN + c) * HWN + y * WN + xcol] = ctr;
            const float* wr = w1 + (size_t)(c * 4) * 9;
            float d[9];
            #pragma unroll
            for (int k = 0; k < 9; ++k) d[k] = ld[cc][k] - ctr;
            unsigned short bq[4];
            #pragma unroll
            for (int e = 0; e < 4; ++e) {
                float a = 0.f;
                #pragma unroll
                for (int k = 0; k < 9; ++k)
                    if (k != 4) a += wr[e * 9 + k] * d[k];
                bq[e] = f2bf(a);
            }
            uint2 uu;
            uu.x = (unsigned)bq[0] | ((unsigned)bq[1] << 16);
            uu.y = (unsigned)bq[2] | ((unsigned)bq[3] << 16);
            *(uint2*)(&xd[px * PITCH + c * 4]) = uu;   // o = 4c..4c+3
        }
    };

    float lbuf[2][4][9];
    load_round(0, lbuf[0]);
    #pragma unroll
    for (int r = 0; r < 4; ++r) {
        if (r < 3) load_round(r + 1, lbuf[(r + 1) & 1]);
        conv_round(r, lbuf[r & 1]);
    }
    __syncthreads();

    // Phase B
    const int lane = tid & 63;
    const int q    = lane >> 4;
    const int c15  = lane & 15;
    const int n0   = wv * 16;

    bf16x8 bfr[8];
    {
        const unsigned short* bp = xd + (size_t)(n0 + c15) * PITCH + q * 8;
        #pragma unroll
        for (int s = 0; s < 8; ++s)
            bfr[s] = *(const bf16x8*)(bp + s * 32);
    }

    f32x4 acc[5];
    #pragma unroll
    for (int t = 0; t < 5; ++t) acc[t] = (f32x4){0.f, 0.f, 0.f, 0.f};

    const bf16x8* ap = (const bf16x8*)w2mf + lane;
    #pragma unroll
    for (int tm = 0; tm < 5; ++tm) {
        #pragma unroll
        for (int s = 0; s < 8; ++s) {
            bf16x8 af = ap[(tm * 8 + s) * 64];
            acc[tm] = __builtin_amdgcn_mfma_f32_16x16x32_bf16(af, bfr[s], acc[tm], 0, 0, 0);
        }
    }

    // Epilogue: add bias, store t (D layout: col=lane&15, row=q*4+reg)
    float* tb = t_out + (size_t)b * JCN * HWN + y * WN + x0 + n0 + c15;
    #pragma unroll
    for (int tm = 0; tm < 5; ++tm) {
        #pragma unroll
        for (int r = 0; r < 4; ++r) {
            int j = tm * 16 + q * 4 + r;
            if (j < JCN)
                tb[(size_t)j * HWN] = acc[tm][r] + b2[j];
        }
    }
}

// ---------------------------------------------------------------------------
// K2: depthwise deformable conv, LDS-staged 2D tile version. (unchanged)
// ---------------------------------------------------------------------------
__device__ __forceinline__ float dsample(const float* __restrict__ p, int yi, int xi) {
    if ((unsigned)yi < (unsigned)HN && (unsigned)xi < (unsigned)WN)
        return p[yi * WN + xi];
    return 0.f;
}

__global__ __launch_bounds__(256, 3) void k_deform(const float* __restrict__ x,
                                                   const float* __restrict__ t_in,
                                                   const float* __restrict__ wdef,
                                                   float* __restrict__ y_out) {
    __shared__ float xs[8 * XH * XW];                 // 27648 B
    __shared__ float ts[9 * DROWS * 32 * 2];          // 18432 B  [k][r][px][dy|dx]
    const int x0   = blockIdx.x * SN;
    const int yr0  = blockIdx.y * DROWS;
    const int zz   = blockIdx.z;
    const int b    = zz >> 3;
    const int chunk = zz & 7;                         // 8-channel chunk
    const int g    = chunk >> 1;                      // deform group
    const int tid  = threadIdx.x;
    const int grp  = tid >> 5;                        // channel within chunk
    const int px   = tid & 31;
    const int c    = chunk * 8 + grp;
    const int row_lo = yr0 - XRT;
    const int col_lo = x0 - XCL;
    const float* xb = x + (size_t)b * CN * HWN;

    for (int idx = tid; idx < 8 * XH * XW; idx += 256) {
        int cc  = idx / (XH * XW);
        int rem = idx - cc * (XH * XW);
        int r   = rem / XW;
        int col = rem - r * XW;
        int yy  = row_lo + r;
        int xx  = col_lo + col;
        float v = 0.f;
        if ((unsigned)yy < (unsigned)HN && (unsigned)xx < (unsigned)WN)
            v = xb[(size_t)(chunk * 8 + cc) * HWN + yy * WN + xx];
        xs[idx] = v;
    }
    const float* tbp = t_in + ((size_t)b * JCN + g * 18) * HWN;
    for (int idx = tid; idx < 18 * DROWS * 32; idx += 256) {
        int j   = idx / (DROWS * 32);
        int rem = idx - j * (DROWS * 32);
        int r   = rem >> 5;
        int cl  = rem & 31;
        float v = tbp[(size_t)j * HWN + (yr0 + r) * WN + x0 + cl];
        int k = j >> 1, comp = j & 1;
        ts[((k * DROWS + r) * 32 + cl) * 2 + comp] = v;
    }
    __syncthreads();

    float wk[9];
    float wsum = 0.f;
    #pragma unroll
    for (int k = 0; k < 9; ++k) { wk[k] = wdef[c * 9 + k]; wsum += wk[k]; }

    const float* xcp = xs + grp * (XH * XW);
    const float* xg  = xb + (size_t)c * HWN;

    float acc[DROWS];
    #pragma unroll
    for (int r = 0; r < DROWS; ++r)
        acc[r] = -xcp[(XRT + r) * XW + XCL + px] * wsum;

    for (int k = 0; k < 9; ++k) {
        const int ky = k / 3, kx = k - 3 * ky;
        #pragma unroll
        for (int r = 0; r < DROWS; ++r) {
            float2 d = *(const float2*)&ts[((k * DROWS + r) * 32 + px) * 2];
            float py  = (float)(yr0 + r - 1 + ky) + d.x;
            float pxf = (float)(x0 + px - 1 + kx) + d.y;
            float y0f = floorf(py);
            float x0f = floorf(pxf);
            float wy = py - y0f;
            float wx = pxf - x0f;
            int yi = (int)y0f;
            int xi = (int)x0f;
            int ry = yi - row_lo;
            int rx = xi - col_lo;
            float v00, v01, v10, v11;
            if ((unsigned)ry < (XH - 1) && (unsigned)rx < (XW - 1)) {
                const float* p = xcp + ry * XW + rx;
                v00 = p[0]; v01 = p[1]; v10 = p[XW]; v11 = p[XW + 1];
            } else {
                v00 = dsample(xg, yi,     xi);
                v01 = dsample(xg, yi,     xi + 1);
                v10 = dsample(xg, yi + 1, xi);
                v11 = dsample(xg, yi + 1, xi + 1);
            }
            float bil = v00 * (1.f - wy) * (1.f - wx)
                      + v01 * (1.f - wy) * wx
                      + v10 * wy * (1.f - wx)
                      + v11 * wy * wx;
            acc[r] += wk[k] * bil;
        }
    }
    #pragma unroll
    for (int r = 0; r < DROWS; ++r)
        y_out[((size_t)b * CN + c) * HWN + (yr0 + r) * WN + x0 + px] = acc[r];
}

// ---------------------------------------------------------------------------
// K3: m[b][o][h][w] = sum_c wout[o][c] * y[b][c][h][w].  64-px tile,
// pre-transposed weights (coalesced staging), 16 o/thread.
// ---------------------------------------------------------------------------
__global__ __launch_bounds__(256, 4) void k_final(const float* __restrict__ y_in,
                                                  const float* __restrict__ w_outT,
                                                  float* __restrict__ m_out) {
    __shared__ float lds_y[CN * 64];     // 16 KB
    __shared__ float ldsw[CN * CN];      // 16 KB  [c][o]
    const int x0  = blockIdx.x * 64;
    const int yr  = blockIdx.y;
    const int b   = blockIdx.z;
    const int tid = threadIdx.x;

    for (int idx = tid; idx < CN * CN; idx += 256) ldsw[idx] = w_outT[idx];
    for (int idx = tid; idx < CN * 64; idx += 256) {
        int c  = idx >> 6;
        int px = idx & 63;
        lds_y[idx] = y_in[((size_t)b * CN + c) * HWN + yr * WN + x0 + px];
    }
    __syncthreads();

    const int px = tid & 63;
    const int og = tid >> 6;                      // 16 o's per thread
    float acc[16];
    #pragma unroll
    for (int i = 0; i < 16; ++i) acc[i] = 0.f;
    #pragma unroll 4
    for (int c = 0; c < CN; ++c) {
        float yv = lds_y[c * 64 + px];
        const float4* wr = (const float4*)(ldsw + c * CN + og * 16);
        float4 w0 = wr[0], w1 = wr[1], w2 = wr[2], w3 = wr[3];
        acc[0]  += w0.x * yv; acc[1]  += w0.y * yv; acc[2]  += w0.z * yv; acc[3]  += w0.w * yv;
        acc[4]  += w1.x * yv; acc[5]  += w1.y * yv; acc[6]  += w1.z * yv; acc[7]  += w1.w * yv;
        acc[8]  += w2.x * yv; acc[9]  += w2.y * yv; acc[10] += w2.z * yv; acc[11] += w2.w * yv;
        acc[12] += w3.x * yv; acc[13] += w3.y * yv; acc[14] += w3.z * yv; acc[15] += w3.w * yv;
    }
    #pragma unroll
    for (int i = 0; i < 16; ++i) {
        int o = og * 16 + i;
        m_out[((size_t)b * CN + o) * HWN + yr * WN + x0 + px] = acc[i];
    }
}

// ---------------------------------------------------------------------------
extern "C" void kernel_launch(void* const* d_in, const int* in_sizes, int n_in,
                              void* d_out, int out_size, void* d_ws, size_t ws_size,
                              hipStream_t stream) {
    const float* x1    = (const float*)d_in[0];   // 2*64*192*192
    const float* w_off1 = (const float*)d_in[1];  // 256*9
    const float* w_off2 = (const float*)d_in[2];  // 72*256
    const float* b_off2 = (const float*)d_in[3];  // 72
    const float* w_def = (const float*)d_in[4];   // 64*9
    const float* w_out = (const float*)d_in[5];   // 64*64

    float* out = (float*)d_out;
    const size_t n_x = (size_t)BN * CN * HWN;     // 4718592
    float* out_x1 = out;                          // output 0: x1 copy (fused into k_offsets)
    float* out_m  = out + n_x;                    // output 1: m

    // Workspace layout (bytes)
    char* ws0 = (char*)d_ws;
    unsigned short* w2mf = (unsigned short*)ws0;            // 20480 bf16 = 40960 B
    float* w_outT = (float*)(ws0 + 40960);                  // 4096 f = 16384 B
    float* t_ws   = (float*)(ws0 + 57344);                  // 2*72*36864 f
    float* y_ws   = t_ws + (size_t)BN * JCN * HWN;          // 2*64*36864 f

    dim3 blk(256);

    k_prep<<<dim3(96), blk, 0, stream>>>(w_off2, w_out, w2mf, w_outT);
    k_offsets<<<dim3(WN / 64, HN, BN), blk, 0, stream>>>(x1, w_off1, w2mf, b_off2,
                                                         t_ws, out_x1);
    k_deform<<<dim3(WN / SN, HN / DROWS, BN * 8), blk, 0, stream>>>(x1, t_ws, w_def, y_ws);
    k_final<<<dim3(WN / 64, HN, BN), blk, 0, stream>>>(y_ws, w_outT, out_m);
}

// Round 6
// 209.774 us; speedup vs baseline: 2.4143x; 1.0701x over previous
//
#include <hip/hip_runtime.h>

// Problem constants (B=2, C=64, H=W=192, EXP=4, DG=4, K=3)
#define BN   2
#define CN   64
#define HN   192
#define WN   192
#define HWN  36864          // 192*192
#define OCN  256            // EXP*C
#define JCN  72             // DG*2*9
#define SN   32             // pixel strip for deform

// k_deform tile geometry
#define DROWS 8             // output rows per block
#define XH    18            // staged x rows
#define XW    48            // staged x cols
#define XRT   5             // row halo top
#define XCL   8             // col halo left

// k_offsets MFMA geometry
#define PITCH 264           // bf16 pitch of xd row (256 + 8 pad)

typedef __attribute__((ext_vector_type(8))) short bf16x8;
typedef __attribute__((ext_vector_type(4))) float f32x4;

__device__ __forceinline__ unsigned short f2bf(float f) {
    union { float f; unsigned u; } v; v.f = f;
    unsigned r = v.u + 0x7fffu + ((v.u >> 16) & 1u);
    return (unsigned short)(r >> 16);
}

// ---------------------------------------------------------------------------
// Prep:
//  job 1: w2mf = w2 (72x256) in bf16, swizzled to MFMA A-fragment order.
//  job 2: w_outT[c*64+o] = w_out[o*64+c]
// ---------------------------------------------------------------------------
__global__ __launch_bounds__(256) void k_prep(const float* __restrict__ w2,
                                              const float* __restrict__ w_out,
                                              unsigned short* __restrict__ w2mf,
                                              float* __restrict__ w_outT) {
    int idx = blockIdx.x * 256 + threadIdx.x;
    if (idx < 20480) {
        int j  = idx & 7;
        int l  = (idx >> 3) & 63;
        int ts = idx >> 9;             // tm*8+s, 0..39
        int tm = ts >> 3, s = ts & 7;
        int jrow = tm * 16 + (l & 15);
        int k    = s * 32 + (l >> 4) * 8 + j;
        float v = (jrow < JCN) ? w2[jrow * OCN + k] : 0.f;
        w2mf[idx] = f2bf(v);
    } else if (idx < 24576) {
        int r = idx - 20480;
        int c = r >> 6, o = r & 63;
        w_outT[r] = w_out[o * CN + c];
    }
}

// ---------------------------------------------------------------------------
// K1: offsets t + fused x1 copy.  MFMA version (unchanged from round 5).
// ---------------------------------------------------------------------------
__global__ __launch_bounds__(256, 4) void k_offsets(const float* __restrict__ x,
                                                    const float* __restrict__ w1,
                                                    const unsigned short* __restrict__ w2mf,
                                                    const float* __restrict__ b2,
                                                    float* __restrict__ t_out,
                                                    float* __restrict__ x_copy) {
    __shared__ unsigned short xd[64 * PITCH];       // 33792 B
    const int x0  = blockIdx.x * 64;
    const int y   = blockIdx.y;
    const int b   = blockIdx.z;
    const int tid = threadIdx.x;
    const int px  = tid & 63;
    const int wv  = tid >> 6;                       // wave id 0..3
    const int xcol = x0 + px;
    const float* xb = x + (size_t)b * CN * HWN;

    auto load_round = [&](int r, float (*ld)[9]) {
        #pragma unroll
        for (int cc = 0; cc < 4; ++cc) {
            int c = r * 16 + cc * 4 + wv;
            const float* xp = xb + (size_t)c * HWN;
            #pragma unroll
            for (int k = 0; k < 9; ++k) {
                int ky = k / 3, kx = k - 3 * ky;
                int yy = y - 1 + ky, xx = xcol - 1 + kx;
                float v = 0.f;
                if ((unsigned)yy < (unsigned)HN && (unsigned)xx < (unsigned)WN)
                    v = xp[yy * WN + xx];
                ld[cc][k] = v;
            }
        }
    };
    auto conv_round = [&](int r, float (*ld)[9]) {
        #pragma unroll
        for (int cc = 0; cc < 4; ++cc) {
            int c = r * 16 + cc * 4 + wv;
            float ctr = ld[cc][4];
            x_copy[((size_t)b * CN + c) * HWN + y * WN + xcol] = ctr;
            const float* wr = w1 + (size_t)(c * 4) * 9;
            float d[9];
            #pragma unroll
            for (int k = 0; k < 9; ++k) d[k] = ld[cc][k] - ctr;
            unsigned short bq[4];
            #pragma unroll
            for (int e = 0; e < 4; ++e) {
                float a = 0.f;
                #pragma unroll
                for (int k = 0; k < 9; ++k)
                    if (k != 4) a += wr[e * 9 + k] * d[k];
                bq[e] = f2bf(a);
            }
            uint2 uu;
            uu.x = (unsigned)bq[0] | ((unsigned)bq[1] << 16);
            uu.y = (unsigned)bq[2] | ((unsigned)bq[3] << 16);
            *(uint2*)(&xd[px * PITCH + c * 4]) = uu;   // o = 4c..4c+3
        }
    };

    float lbuf[2][4][9];
    load_round(0, lbuf[0]);
    #pragma unroll
    for (int r = 0; r < 4; ++r) {
        if (r < 3) load_round(r + 1, lbuf[(r + 1) & 1]);
        conv_round(r, lbuf[r & 1]);
    }
    __syncthreads();

    // Phase B
    const int lane = tid & 63;
    const int q    = lane >> 4;
    const int c15  = lane & 15;
    const int n0   = wv * 16;

    bf16x8 bfr[8];
    {
        const unsigned short* bp = xd + (size_t)(n0 + c15) * PITCH + q * 8;
        #pragma unroll
        for (int s = 0; s < 8; ++s)
            bfr[s] = *(const bf16x8*)(bp + s * 32);
    }

    f32x4 acc[5];
    #pragma unroll
    for (int t = 0; t < 5; ++t) acc[t] = (f32x4){0.f, 0.f, 0.f, 0.f};

    const bf16x8* ap = (const bf16x8*)w2mf + lane;
    #pragma unroll
    for (int tm = 0; tm < 5; ++tm) {
        #pragma unroll
        for (int s = 0; s < 8; ++s) {
            bf16x8 af = ap[(tm * 8 + s) * 64];
            acc[tm] = __builtin_amdgcn_mfma_f32_16x16x32_bf16(af, bfr[s], acc[tm], 0, 0, 0);
        }
    }

    float* tb = t_out + (size_t)b * JCN * HWN + y * WN + x0 + n0 + c15;
    #pragma unroll
    for (int tm = 0; tm < 5; ++tm) {
        #pragma unroll
        for (int r = 0; r < 4; ++r) {
            int j = tm * 16 + q * 4 + r;
            if (j < JCN)
                tb[(size_t)j * HWN] = acc[tm][r] + b2[j];
        }
    }
}

// ---------------------------------------------------------------------------
// K2: depthwise deformable conv, channel-inner-loop version.
// Thread = (row r, px); loops 8 channels inside each tap so offset/weight
// math is computed ONCE per tap (shared across channels). ts stored as
// separate dy/dx planes (conflict-free b32).
// ---------------------------------------------------------------------------
__device__ __forceinline__ float dsample(const float* __restrict__ p, int yi, int xi) {
    if ((unsigned)yi < (unsigned)HN && (unsigned)xi < (unsigned)WN)
        return p[yi * WN + xi];
    return 0.f;
}

__global__ __launch_bounds__(256, 3) void k_deform(const float* __restrict__ x,
                                                   const float* __restrict__ t_in,
                                                   const float* __restrict__ wdef,
                                                   float* __restrict__ y_out) {
    __shared__ float xs[8 * XH * XW];                 // 27648 B
    __shared__ float ts[2][9][DROWS][32];             // 18432 B [comp][k][r][px]
    __shared__ float wks[9 * 8];                      // [k][cc]
    __shared__ float wsums[8];
    const int x0   = blockIdx.x * SN;
    const int yr0  = blockIdx.y * DROWS;
    const int zz   = blockIdx.z;
    const int b    = zz >> 3;
    const int chunk = zz & 7;                         // 8-channel chunk
    const int g    = chunk >> 1;                      // deform group
    const int tid  = threadIdx.x;
    const int r    = tid >> 5;                        // output row within tile
    const int px   = tid & 31;
    const int row_lo = yr0 - XRT;
    const int col_lo = x0 - XCL;
    const float* xb = x + (size_t)b * CN * HWN;

    // stage x window (zero-filled outside image)
    for (int idx = tid; idx < 8 * XH * XW; idx += 256) {
        int cc  = idx / (XH * XW);
        int rem = idx - cc * (XH * XW);
        int rr  = rem / XW;
        int col = rem - rr * XW;
        int yy  = row_lo + rr;
        int xx  = col_lo + col;
        float v = 0.f;
        if ((unsigned)yy < (unsigned)HN && (unsigned)xx < (unsigned)WN)
            v = xb[(size_t)(chunk * 8 + cc) * HWN + yy * WN + xx];
        xs[idx] = v;
    }
    // stage offsets: separate dy/dx planes
    const float* tbp = t_in + ((size_t)b * JCN + g * 18) * HWN;
    for (int idx = tid; idx < 18 * DROWS * 32; idx += 256) {
        int j   = idx >> 8;            // 0..17
        int rem = idx & 255;
        int rr  = rem >> 5;
        int cl  = rem & 31;
        float v = tbp[(size_t)j * HWN + (yr0 + rr) * WN + x0 + cl];
        int k = j >> 1, comp = j & 1;
        ts[comp][k][rr][cl] = v;
    }
    // stage weights
    if (tid < 72) {
        int k = tid >> 3, cc = tid & 7;
        wks[tid] = wdef[(chunk * 8 + cc) * 9 + k];
    } else if (tid < 80) {
        int cc = tid - 72;
        float s = 0.f;
        #pragma unroll
        for (int k = 0; k < 9; ++k) s += wdef[(chunk * 8 + cc) * 9 + k];
        wsums[cc] = s;
    }
    __syncthreads();

    float acc[8];
    #pragma unroll
    for (int c = 0; c < 8; ++c)
        acc[c] = -xs[c * (XH * XW) + (XRT + r) * XW + XCL + px] * wsums[c];

    const float ry_basef = (float)(yr0 + r - 1);
    const float rx_basef = (float)(x0 + px - 1);

    #pragma unroll
    for (int k = 0; k < 9; ++k) {
        const int ky = k / 3, kx = k - 3 * ky;
        float dy = ts[0][k][r][px];
        float dx = ts[1][k][r][px];
        float py  = ry_basef + (float)ky + dy;
        float pxf = rx_basef + (float)kx + dx;
        float y0f = floorf(py), x0f = floorf(pxf);
        float wy = py - y0f, wx = pxf - x0f;
        int yi = (int)y0f, xi = (int)x0f;
        int ry = yi - row_lo, rx = xi - col_lo;
        float omwy = 1.f - wy, omwx = 1.f - wx;
        float w00 = omwy * omwx;
        float w01 = omwy * wx;
        float w10 = wy * omwx;
        float w11 = wy * wx;
        float4 wka = *(const float4*)&wks[k * 8];
        float4 wkb = *(const float4*)&wks[k * 8 + 4];
        float wkv[8] = {wka.x, wka.y, wka.z, wka.w, wkb.x, wkb.y, wkb.z, wkb.w};
        if ((unsigned)ry < (XH - 1) && (unsigned)rx < (XW - 1)) {
            const float* p0 = xs + ry * XW + rx;
            #pragma unroll
            for (int c = 0; c < 8; ++c) {
                const float* p = p0 + c * (XH * XW);
                float bil = p[0] * w00 + p[1] * w01 + p[XW] * w10 + p[XW + 1] * w11;
                acc[c] += wkv[c] * bil;
            }
        } else {
            #pragma unroll
            for (int c = 0; c < 8; ++c) {
                const float* xp = xb + (size_t)(chunk * 8 + c) * HWN;
                float v00 = dsample(xp, yi,     xi);
                float v01 = dsample(xp, yi,     xi + 1);
                float v10 = dsample(xp, yi + 1, xi);
                float v11 = dsample(xp, yi + 1, xi + 1);
                float bil = v00 * w00 + v01 * w01 + v10 * w10 + v11 * w11;
                acc[c] += wkv[c] * bil;
            }
        }
    }

    float* yo = y_out + ((size_t)b * CN + chunk * 8) * HWN + (yr0 + r) * WN + x0 + px;
    #pragma unroll
    for (int c = 0; c < 8; ++c)
        yo[(size_t)c * HWN] = acc[c];
}

// ---------------------------------------------------------------------------
// K3: m = w_out . y  (64-px tile, pre-transposed weights, 16 o/thread)
// ---------------------------------------------------------------------------
__global__ __launch_bounds__(256, 4) void k_final(const float* __restrict__ y_in,
                                                  const float* __restrict__ w_outT,
                                                  float* __restrict__ m_out) {
    __shared__ float lds_y[CN * 64];     // 16 KB
    __shared__ float ldsw[CN * CN];      // 16 KB  [c][o]
    const int x0  = blockIdx.x * 64;
    const int yr  = blockIdx.y;
    const int b   = blockIdx.z;
    const int tid = threadIdx.x;

    for (int idx = tid; idx < CN * CN; idx += 256) ldsw[idx] = w_outT[idx];
    for (int idx = tid; idx < CN * 64; idx += 256) {
        int c  = idx >> 6;
        int px = idx & 63;
        lds_y[idx] = y_in[((size_t)b * CN + c) * HWN + yr * WN + x0 + px];
    }
    __syncthreads();

    const int px = tid & 63;
    const int og = tid >> 6;                      // 16 o's per thread
    float acc[16];
    #pragma unroll
    for (int i = 0; i < 16; ++i) acc[i] = 0.f;
    #pragma unroll 4
    for (int c = 0; c < CN; ++c) {
        float yv = lds_y[c * 64 + px];
        const float4* wr = (const float4*)(ldsw + c * CN + og * 16);
        float4 w0 = wr[0], w1 = wr[1], w2 = wr[2], w3 = wr[3];
        acc[0]  += w0.x * yv; acc[1]  += w0.y * yv; acc[2]  += w0.z * yv; acc[3]  += w0.w * yv;
        acc[4]  += w1.x * yv; acc[5]  += w1.y * yv; acc[6]  += w1.z * yv; acc[7]  += w1.w * yv;
        acc[8]  += w2.x * yv; acc[9]  += w2.y * yv; acc[10] += w2.z * yv; acc[11] += w2.w * yv;
        acc[12] += w3.x * yv; acc[13] += w3.y * yv; acc[14] += w3.z * yv; acc[15] += w3.w * yv;
    }
    #pragma unroll
    for (int i = 0; i < 16; ++i) {
        int o = og * 16 + i;
        m_out[((size_t)b * CN + o) * HWN + yr * WN + x0 + px] = acc[i];
    }
}

// ---------------------------------------------------------------------------
extern "C" void kernel_launch(void* const* d_in, const int* in_sizes, int n_in,
                              void* d_out, int out_size, void* d_ws, size_t ws_size,
                              hipStream_t stream) {
    const float* x1    = (const float*)d_in[0];   // 2*64*192*192
    const float* w_off1 = (const float*)d_in[1];  // 256*9
    const float* w_off2 = (const float*)d_in[2];  // 72*256
    const float* b_off2 = (const float*)d_in[3];  // 72
    const float* w_def = (const float*)d_in[4];   // 64*9
    const float* w_out = (const float*)d_in[5];   // 64*64

    float* out = (float*)d_out;
    const size_t n_x = (size_t)BN * CN * HWN;     // 4718592
    float* out_x1 = out;                          // output 0: x1 copy (fused into k_offsets)
    float* out_m  = out + n_x;                    // output 1: m

    // Workspace layout (bytes)
    char* ws0 = (char*)d_ws;
    unsigned short* w2mf = (unsigned short*)ws0;            // 20480 bf16 = 40960 B
    float* w_outT = (float*)(ws0 + 40960);                  // 4096 f = 16384 B
    float* t_ws   = (float*)(ws0 + 57344);                  // 2*72*36864 f
    float* y_ws   = t_ws + (size_t)BN * JCN * HWN;          // 2*64*36864 f

    dim3 blk(256);

    k_prep<<<dim3(96), blk, 0, stream>>>(w_off2, w_out, w2mf, w_outT);
    k_offsets<<<dim3(WN / 64, HN, BN), blk, 0, stream>>>(x1, w_off1, w2mf, b_off2,
                                                         t_ws, out_x1);
    k_deform<<<dim3(WN / SN, HN / DROWS, BN * 8), blk, 0, stream>>>(x1, t_ws, w_def, y_ws);
    k_final<<<dim3(WN / 64, HN, BN), blk, 0, stream>>>(y_ws, w_outT, out_m);
}